// Round 6
// baseline (157.830 us; speedup 1.0000x reference)
//
#include <hip/hip_runtime.h>
#include <math.h>

#define BLOCK 256
#define GRID 2048
#define FBLOCK 1024

__global__ __launch_bounds__(BLOCK) void ratledge_partial(
    const float* __restrict__ yp, const float* __restrict__ yt,
    const float* __restrict__ quants, float* __restrict__ partial, int n)
{
    // quants: uniform address -> compiler scalarizes to s_load
    float q[6];
#pragma unroll
    for (int j = 0; j < 6; ++j) q[j] = quants[j];
    const float q5 = q[5];

    float msum = 0.f;
    // suffix accumulators: ss[j] = sum of d over {q_j <= v <= q5}; sc[j] = count
    float ss[5] = {0.f, 0.f, 0.f, 0.f, 0.f};
    unsigned sc[5] = {0u, 0u, 0u, 0u, 0u};

    const int tid    = blockIdx.x * BLOCK + threadIdx.x;
    const int stride = GRID * BLOCK;
    const int n4     = n >> 2;
    const float4* yp4 = (const float4*)yp;
    const float4* yt4 = (const float4*)yt;

    auto body1 = [&](float p, float v) {
        float d = p - v;
        msum = fmaf(d, d, msum);
        // invalid-high (v > q5, incl. NaN) -> -inf fails every v>=q_j test.
        // v == q5 passes all 5 -> bin 4 via differencing. Exact searchsorted
        // (side='right') semantics.
        float vv = (v <= q5) ? v : -INFINITY;
#pragma unroll
        for (int j = 0; j < 5; ++j) {
            bool m = (vv >= q[j]);
            ss[j] += m ? d : 0.f;
            sc[j] += m ? 1u : 0u;
        }
    };
    auto body4 = [&](const float4& p, const float4& t) {
        body1(p.x, t.x); body1(p.y, t.y); body1(p.z, t.z); body1(p.w, t.w);
    };

    const int trips = n4 / stride;                 // n=2^24: trips = 8
    const int kmain = (trips >= 4) ? (trips & ~3) : 0;

    if (kmain) {
        // Software pipeline, depth 1, static A/B double buffer (rule #20:
        // no runtime-indexed buffers). sched_barrier(0) fences stop the
        // compiler from sinking loads into the compute region (rule #18).
        float4 Pa0, Ta0, Pa1, Ta1;
        {
            const int ia = tid;
            Pa0 = yp4[ia];          Ta0 = yt4[ia];
            Pa1 = yp4[ia + stride]; Ta1 = yt4[ia + stride];
        }
        for (int k = 0; k < kmain; k += 4) {
            // issue B-group loads (iters k+2, k+3) before computing A
            const int ib = tid + (k + 2) * stride;
            float4 Pb0 = yp4[ib];          float4 Tb0 = yt4[ib];
            float4 Pb1 = yp4[ib + stride]; float4 Tb1 = yt4[ib + stride];
            __builtin_amdgcn_sched_barrier(0);
            body4(Pa0, Ta0); body4(Pa1, Ta1);
            if (k + 4 < kmain) {           // uniform branch
                const int ia = tid + (k + 4) * stride;
                Pa0 = yp4[ia];          Ta0 = yt4[ia];
                Pa1 = yp4[ia + stride]; Ta1 = yt4[ia + stride];
            }
            __builtin_amdgcn_sched_barrier(0);
            body4(Pb0, Tb0); body4(Pb1, Tb1);
        }
    }
    // leftover full trips (trips % 4)
    for (int k = kmain; k < trips; ++k) {
        const int i = tid + k * stride;
        float4 p = yp4[i];
        float4 t = yt4[i];
        body4(p, t);
    }
    // remainder float4s (n4 % stride)
    {
        const int i = tid + trips * stride;
        if (i < n4) {
            float4 p = yp4[i];
            float4 t = yt4[i];
            body4(p, t);
        }
    }
    // scalar tail (n % 4)
    for (int i = (n4 << 2) + tid; i < n; i += stride)
        body1(yp[i], yt[i]);

    // wave64 shuffle reduce of 11 partials
    float vals[11];
    vals[0] = msum;
#pragma unroll
    for (int j = 0; j < 5; ++j) { vals[1 + j] = ss[j]; vals[6 + j] = (float)sc[j]; }
#pragma unroll
    for (int off = 32; off > 0; off >>= 1) {
#pragma unroll
        for (int j = 0; j < 11; ++j)
            vals[j] += __shfl_down(vals[j], off, 64);
    }

    __shared__ float sred[BLOCK / 64][11];
    const int lane = threadIdx.x & 63;
    const int wid  = threadIdx.x >> 6;
    if (lane == 0) {
#pragma unroll
        for (int j = 0; j < 11; ++j) sred[wid][j] = vals[j];
    }
    __syncthreads();
    if (threadIdx.x == 0) {
#pragma unroll
        for (int j = 0; j < 11; ++j) {
            float s = sred[0][j] + sred[1][j] + sred[2][j] + sred[3][j];
            partial[j * GRID + blockIdx.x] = s;  // SoA: coalesced in finalize
        }
    }
}

__global__ __launch_bounds__(FBLOCK) void ratledge_final(
    const float* __restrict__ partial, float* __restrict__ out, int n)
{
    const int t    = threadIdx.x;
    const int lane = t & 63;
    const int wid  = t >> 6;   // 0..15

    // Each thread: 2 coalesced loads per slot (GRID=2048, FBLOCK=1024).
    double acc[11];
#pragma unroll
    for (int j = 0; j < 11; ++j) {
        float a0 = partial[j * GRID + t];
        float a1 = partial[j * GRID + t + FBLOCK];
        acc[j] = (double)a0 + (double)a1;
    }

#pragma unroll
    for (int off = 32; off > 0; off >>= 1) {
#pragma unroll
        for (int j = 0; j < 11; ++j)
            acc[j] += __shfl_down(acc[j], off, 64);
    }

    __shared__ double sred[FBLOCK / 64][11];
    if (lane == 0) {
#pragma unroll
        for (int j = 0; j < 11; ++j) sred[wid][j] = acc[j];
    }
    __syncthreads();

    if (wid == 0) {
        double v[11];
#pragma unroll
        for (int j = 0; j < 11; ++j)
            v[j] = (lane < FBLOCK / 64) ? sred[lane][j] : 0.0;
#pragma unroll
        for (int off = 8; off > 0; off >>= 1) {
#pragma unroll
            for (int j = 0; j < 11; ++j)
                v[j] += __shfl_down(v[j], off, 64);
        }
        if (lane == 0) {
            double mse = v[0] / (double)n;
            double maxb2 = 0.0;  // torch starts from tensor(0.0)
            // un-difference the suffix accumulators: bin j = suffix j - suffix j+1
#pragma unroll
            for (int j = 0; j < 5; ++j) {
                double Sj  = v[1 + j];
                double Sj1 = (j < 4) ? v[2 + j] : 0.0;
                double Cj  = v[6 + j];
                double Cj1 = (j < 4) ? v[7 + j] : 0.0;
                double cnt = Cj - Cj1;
                double sum = Sj - Sj1;
                double bias = sum / fmax(cnt, 1.0);
                double b2   = (cnt > 0.0) ? bias * bias : 0.0;
                maxb2 = fmax(maxb2, b2);
            }
            out[0] = (float)(mse + 5.0 * maxb2);
        }
    }
}

extern "C" void kernel_launch(void* const* d_in, const int* in_sizes, int n_in,
                              void* d_out, int out_size, void* d_ws, size_t ws_size,
                              hipStream_t stream) {
    const float* yp = (const float*)d_in[0];
    const float* yt = (const float*)d_in[1];
    const float* q  = (const float*)d_in[2];
    float* partial  = (float*)d_ws;          // GRID*11*4 = 90112 B
    float* out      = (float*)d_out;
    int n = in_sizes[0];

    ratledge_partial<<<GRID, BLOCK, 0, stream>>>(yp, yt, q, partial, n);
    ratledge_final<<<1, FBLOCK, 0, stream>>>(partial, out, n);
}

// Round 7
// 156.053 us; speedup vs baseline: 1.0114x; 1.0114x over previous
//
#include <hip/hip_runtime.h>
#include <math.h>

#define BLOCK 256
#define GRID 2048
#define FBLOCK 1024

__global__ __launch_bounds__(BLOCK) void ratledge_partial(
    const float* __restrict__ yp, const float* __restrict__ yt,
    const float* __restrict__ quants, float* __restrict__ partial, int n)
{
    // quants: uniform address -> scalar loads
    float q[6];
#pragma unroll
    for (int j = 0; j < 6; ++j) q[j] = quants[j];
    const float q5 = q[5];

    float msum = 0.f;
    // suffix accumulators: ss[j] = sum of d over {q_j <= v <= q5}; sc[j] = count
    float ss[5] = {0.f, 0.f, 0.f, 0.f, 0.f};
    float sc[5] = {0.f, 0.f, 0.f, 0.f, 0.f};

    const int tid    = blockIdx.x * BLOCK + threadIdx.x;
    const int stride = GRID * BLOCK;
    const int n4     = n >> 2;
    const float4* yp4 = (const float4*)yp;
    const float4* yt4 = (const float4*)yt;

    auto body1 = [&](float p, float v) {
        float d = p - v;
        msum = fmaf(d, d, msum);
        // invalid-high (v > q5, incl. NaN) -> -inf fails every v>=q_j test.
        // v == q5 passes all 5 -> bin 4 via differencing. Exact
        // searchsorted(side='right') semantics.
        float vv = (v <= q5) ? v : -INFINITY;
#pragma unroll
        for (int j = 0; j < 5; ++j) {
            bool m = (vv >= q[j]);
            ss[j] += m ? d   : 0.f;
            sc[j] += m ? 1.f : 0.f;
        }
    };
    auto body4 = [&](const float4& p, const float4& t) {
        body1(p.x, t.x); body1(p.y, t.y); body1(p.z, t.z); body1(p.w, t.w);
    };

    if (n == stride * 32) {
        // ===== static fast path (N = GRID*BLOCK*32, e.g. 2^24) =====
        // Issue ALL 16 dwordx4 loads back-to-back into registers, THEN compute.
        // Single basic block + sched_barrier fence: the scheduler cannot sink
        // the loads next to their uses, so up to 16 stay in flight per wave.
        float4 P[8], T[8];
#pragma unroll
        for (int r = 0; r < 8; ++r) {
            const int i = tid + r * stride;
            P[r] = yp4[i];
            T[r] = yt4[i];
        }
        __builtin_amdgcn_sched_barrier(0);
#pragma unroll
        for (int r = 0; r < 8; ++r)
            body4(P[r], T[r]);
    } else {
        // ===== generic path (any n) =====
        const int trips = n4 / stride;
        for (int k = 0; k < trips; ++k) {
            const int i = tid + k * stride;
            float4 p = yp4[i];
            float4 t = yt4[i];
            body4(p, t);
        }
        const int i = tid + trips * stride;
        if (i < n4) {
            float4 p = yp4[i];
            float4 t = yt4[i];
            body4(p, t);
        }
        for (int i2 = (n4 << 2) + tid; i2 < n; i2 += stride)
            body1(yp[i2], yt[i2]);
    }

    // wave64 shuffle reduce of 11 partials
    float vals[11];
    vals[0] = msum;
#pragma unroll
    for (int j = 0; j < 5; ++j) { vals[1 + j] = ss[j]; vals[6 + j] = sc[j]; }
#pragma unroll
    for (int off = 32; off > 0; off >>= 1) {
#pragma unroll
        for (int j = 0; j < 11; ++j)
            vals[j] += __shfl_down(vals[j], off, 64);
    }

    __shared__ float sred[BLOCK / 64][11];
    const int lane = threadIdx.x & 63;
    const int wid  = threadIdx.x >> 6;
    if (lane == 0) {
#pragma unroll
        for (int j = 0; j < 11; ++j) sred[wid][j] = vals[j];
    }
    __syncthreads();
    if (threadIdx.x == 0) {
#pragma unroll
        for (int j = 0; j < 11; ++j) {
            float s = sred[0][j] + sred[1][j] + sred[2][j] + sred[3][j];
            partial[j * GRID + blockIdx.x] = s;  // SoA: coalesced in finalize
        }
    }
}

__global__ __launch_bounds__(FBLOCK) void ratledge_final(
    const float* __restrict__ partial, float* __restrict__ out, int n)
{
    const int t    = threadIdx.x;
    const int lane = t & 63;
    const int wid  = t >> 6;   // 0..15

    // Each thread: 2 coalesced loads per slot (GRID=2048, FBLOCK=1024).
    double acc[11];
#pragma unroll
    for (int j = 0; j < 11; ++j) {
        float a0 = partial[j * GRID + t];
        float a1 = partial[j * GRID + t + FBLOCK];
        acc[j] = (double)a0 + (double)a1;
    }

#pragma unroll
    for (int off = 32; off > 0; off >>= 1) {
#pragma unroll
        for (int j = 0; j < 11; ++j)
            acc[j] += __shfl_down(acc[j], off, 64);
    }

    __shared__ double sred[FBLOCK / 64][11];
    if (lane == 0) {
#pragma unroll
        for (int j = 0; j < 11; ++j) sred[wid][j] = acc[j];
    }
    __syncthreads();

    if (wid == 0) {
        double v[11];
#pragma unroll
        for (int j = 0; j < 11; ++j)
            v[j] = (lane < FBLOCK / 64) ? sred[lane][j] : 0.0;
#pragma unroll
        for (int off = 8; off > 0; off >>= 1) {
#pragma unroll
            for (int j = 0; j < 11; ++j)
                v[j] += __shfl_down(v[j], off, 64);
        }
        if (lane == 0) {
            double mse = v[0] / (double)n;
            double maxb2 = 0.0;  // torch starts from tensor(0.0)
            // un-difference the suffix accumulators: bin j = suffix j - suffix j+1
#pragma unroll
            for (int j = 0; j < 5; ++j) {
                double Sj  = v[1 + j];
                double Sj1 = (j < 4) ? v[2 + j] : 0.0;
                double Cj  = v[6 + j];
                double Cj1 = (j < 4) ? v[7 + j] : 0.0;
                double cnt = Cj - Cj1;
                double sum = Sj - Sj1;
                double bias = sum / fmax(cnt, 1.0);
                double b2   = (cnt > 0.0) ? bias * bias : 0.0;
                maxb2 = fmax(maxb2, b2);
            }
            out[0] = (float)(mse + 5.0 * maxb2);
        }
    }
}

extern "C" void kernel_launch(void* const* d_in, const int* in_sizes, int n_in,
                              void* d_out, int out_size, void* d_ws, size_t ws_size,
                              hipStream_t stream) {
    const float* yp = (const float*)d_in[0];
    const float* yt = (const float*)d_in[1];
    const float* q  = (const float*)d_in[2];
    float* partial  = (float*)d_ws;          // GRID*11*4 = 90112 B
    float* out      = (float*)d_out;
    int n = in_sizes[0];

    ratledge_partial<<<GRID, BLOCK, 0, stream>>>(yp, yt, q, partial, n);
    ratledge_final<<<1, FBLOCK, 0, stream>>>(partial, out, n);
}